// Round 1
// baseline (646.942 us; speedup 1.0000x reference)
//
#include <hip/hip_runtime.h>

#define NTOK 49
#define HEADS 6
#define CDIM 192
#define NWIN 4096

typedef unsigned short u16;
typedef unsigned int u32;
typedef unsigned long long u64;
typedef __attribute__((ext_vector_type(8))) __bf16 bf16x8;
typedef __attribute__((ext_vector_type(4))) float floatx4;

// LDS layout (bytes)
#define OFF_X 0         // [64][200] u16 bf16 (X, later AO)
#define OFF_Q 25600     // [64][200]
#define OFF_K 51200     // [64][200]
#define OFF_V 76800     // [192][72]  Vt[ch][tok]
#define OFF_P 104448    // [8 waves][16][72]
#define LDS_BYTES 122880

__device__ __forceinline__ u16 f2bf(float f) {
  union { float f; u32 u; } v; v.f = f;
  u32 u = v.u;
  u = (u + 0x7FFFu + ((u >> 16) & 1u)) >> 16;
  return (u16)u;
}
__device__ __forceinline__ float bf2f(u16 u) {
  union { u32 u; float f; } v; v.u = ((u32)u) << 16;
  return v.f;
}
__device__ __forceinline__ void st4bf(u16* p, float a, float b, float c, float d) {
  u64 t = (u64)f2bf(a) | ((u64)f2bf(b) << 16) | ((u64)f2bf(c) << 32) | ((u64)f2bf(d) << 48);
  *(u64*)p = t;
}

__global__ __launch_bounds__(256)
void wprep(const float* __restrict__ Wq, const float* __restrict__ Wk,
           const float* __restrict__ Wv, const float* __restrict__ Wp,
           const float* __restrict__ rpb, const int* __restrict__ rel,
           u16* __restrict__ w_bf, float* __restrict__ bias) {
  const int tid = blockIdx.x * blockDim.x + threadIdx.x;
  const int stride = gridDim.x * blockDim.x;
  for (int i = tid; i < 4 * CDIM * CDIM; i += stride) {
    const int p = i / (CDIM * CDIM), e = i % (CDIM * CDIM);
    float v = (p == 0) ? Wq[e] : (p == 1) ? Wk[e] : (p == 2) ? Wv[e] : Wp[e];
    w_bf[i] = f2bf(v);
  }
  for (int i = tid; i < HEADS * NTOK * NTOK; i += stride) {
    const int h = i / (NTOK * NTOK), nm = i % (NTOK * NTOK);
    bias[i] = rpb[rel[nm] * HEADS + h];
  }
}

__global__ __launch_bounds__(512, 2)
void wattn_main(const float* __restrict__ x, const float* __restrict__ mask,
                const float* __restrict__ d_l, const float* __restrict__ temp,
                const u16* __restrict__ w_bf, const float* __restrict__ bias,
                float* __restrict__ out) {
  extern __shared__ __align__(16) char smem[];
  u16* Xb = (u16*)(smem + OFF_X);
  u16* Qn = (u16*)(smem + OFF_Q);
  u16* Kn = (u16*)(smem + OFF_K);
  u16* Vt = (u16*)(smem + OFF_V);
  u16* Pw = (u16*)(smem + OFF_P);

  const int b = blockIdx.x;
  const int tid = threadIdx.x;
  const int wave = tid >> 6;
  const int lane = tid & 63;
  const int g = lane >> 4;
  const int nl = lane & 15;

  // ---- phase 0: stage x -> bf16 LDS, zero pad rows 49..63
  {
    const float* xb = x + (size_t)b * (NTOK * CDIM);
    for (int i = tid; i < NTOK * CDIM / 4; i += 512) {
      const int n = i / 48;
      const int c = (i - n * 48) * 4;
      const float4 v = *(const float4*)(xb + n * CDIM + c);
      st4bf(Xb + n * 200 + c, v.x, v.y, v.z, v.w);
    }
    for (int i = tid; i < 15 * 48; i += 512) {
      const int n = 49 + i / 48;
      const int c = (i % 48) * 4;
      *(u64*)(Xb + n * 200 + c) = 0ull;
    }
  }
  __syncthreads();

  // ---- phase 1: QKV projections (Q^T=Wq*X^T, K^T=Wk*X^T -> row-major Q/K; V=X*Wv^T -> Vt)
  {
    bf16x8 xf[4][6];
#pragma unroll
    for (int nt = 0; nt < 4; ++nt)
#pragma unroll
      for (int k = 0; k < 6; ++k)
        xf[nt][k] = *(const bf16x8*)(Xb + (nt * 16 + nl) * 200 + k * 32 + g * 8);

    for (int u = wave; u < 36; u += 8) {
      const int p = u / 12, o = u % 12;
      const u16* wb = w_bf + p * (CDIM * CDIM) + (o * 16 + nl) * CDIM + g * 8;
      bf16x8 wf[6];
#pragma unroll
      for (int k = 0; k < 6; ++k) wf[k] = *(const bf16x8*)(wb + k * 32);
      floatx4 acc[4];
#pragma unroll
      for (int nt = 0; nt < 4; ++nt) acc[nt] = (floatx4){0.f, 0.f, 0.f, 0.f};
      if (p < 2) {
#pragma unroll
        for (int k = 0; k < 6; ++k)
#pragma unroll
          for (int nt = 0; nt < 4; ++nt)
            acc[nt] = __builtin_amdgcn_mfma_f32_16x16x32_bf16(wf[k], xf[nt][k], acc[nt], 0, 0, 0);
        u16* dst = (p == 0 ? Qn : Kn);
#pragma unroll
        for (int nt = 0; nt < 4; ++nt)
          st4bf(dst + (nt * 16 + nl) * 200 + o * 16 + g * 4,
                acc[nt][0], acc[nt][1], acc[nt][2], acc[nt][3]);
      } else {
#pragma unroll
        for (int k = 0; k < 6; ++k)
#pragma unroll
          for (int nt = 0; nt < 4; ++nt)
            acc[nt] = __builtin_amdgcn_mfma_f32_16x16x32_bf16(xf[nt][k], wf[k], acc[nt], 0, 0, 0);
#pragma unroll
        for (int nt = 0; nt < 4; ++nt)
          st4bf(Vt + (o * 16 + nl) * 72 + nt * 16 + g * 4,
                acc[nt][0], acc[nt][1], acc[nt][2], acc[nt][3]);
      }
    }
  }
  __syncthreads();

  // ---- phase 2: l2-normalize Q,K rows (per (tensor,head,token), 4 lanes/row)
  {
    const int sub = tid & 3;
    for (int ru = tid >> 2; ru < 2 * HEADS * NTOK; ru += 128) {
      const int t = ru / (HEADS * NTOK);
      const int rem = ru - t * (HEADS * NTOK);
      const int h = rem / NTOK, n = rem - h * NTOK;
      u16* base = (t == 0 ? Qn : Kn) + n * 200 + h * 32 + sub * 8;
      u64 lo = *(u64*)base;
      u64 hi = *(u64*)(base + 4);
      float f[8];
#pragma unroll
      for (int e = 0; e < 4; ++e) f[e] = bf2f((u16)(lo >> (16 * e)));
#pragma unroll
      for (int e = 0; e < 4; ++e) f[4 + e] = bf2f((u16)(hi >> (16 * e)));
      float ss = 0.f;
#pragma unroll
      for (int e = 0; e < 8; ++e) ss += f[e] * f[e];
      ss += __shfl_xor(ss, 1);
      ss += __shfl_xor(ss, 2);
      const float inv = 1.0f / fmaxf(sqrtf(ss), 1e-12f);
      st4bf(base, f[0] * inv, f[1] * inv, f[2] * inv, f[3] * inv);
      st4bf(base + 4, f[4] * inv, f[5] * inv, f[6] * inv, f[7] * inv);
    }
  }
  __syncthreads();

  // ---- phase 3: attention per (head, n-tile): S^T = K*Q^T, softmax over rows(m), O^T = Vt*P
  {
    const float dl = d_l[b];
    const int wmask = b & (NWIN - 1);
    u16* Pb = Pw + wave * (16 * 72);
    for (int t = wave; t < 24; t += 8) {
      const int h = t >> 2, nt2 = t & 3;
      const int n = nt2 * 16 + nl;
      const int ncl = n < 49 ? n : 48;
      const float tdl = temp[h] * dl;
      const bf16x8 qf = *(const bf16x8*)(Qn + n * 200 + h * 32 + g * 8);
      floatx4 sacc[4];
#pragma unroll
      for (int rt = 0; rt < 4; ++rt) {
        const bf16x8 kf = *(const bf16x8*)(Kn + (rt * 16 + nl) * 200 + h * 32 + g * 8);
        sacc[rt] = __builtin_amdgcn_mfma_f32_16x16x32_bf16(kf, qf, (floatx4){0.f, 0.f, 0.f, 0.f}, 0, 0, 0);
      }
      const float* brow = bias + (h * NTOK + ncl) * NTOK;
      const float* mrow = mask + ((size_t)wmask * NTOK + ncl) * NTOK;
      float L[4][4];
      float pmax = -1e30f;
#pragma unroll
      for (int rt = 0; rt < 4; ++rt)
#pragma unroll
        for (int r = 0; r < 4; ++r) {
          const int m = rt * 16 + g * 4 + r;
          const int mcl = m < 49 ? m : 48;
          const float bm = (brow[mcl] + mrow[mcl]) * dl;
          float lv = fmaf(sacc[rt][r], tdl, bm);
          lv = (m < 49) ? lv : -1e30f;
          L[rt][r] = lv;
          pmax = fmaxf(pmax, lv);
        }
      pmax = fmaxf(pmax, __shfl_xor(pmax, 16));
      pmax = fmaxf(pmax, __shfl_xor(pmax, 32));
      float psum = 0.f;
#pragma unroll
      for (int rt = 0; rt < 4; ++rt)
#pragma unroll
        for (int r = 0; r < 4; ++r) {
          const int m = rt * 16 + g * 4 + r;
          const float e = (m < 49) ? __expf(L[rt][r] - pmax) : 0.f;
          L[rt][r] = e;
          psum += e;
        }
      psum += __shfl_xor(psum, 16);
      psum += __shfl_xor(psum, 32);
      const float rinv = 1.0f / psum;
#pragma unroll
      for (int rt = 0; rt < 4; ++rt)
        st4bf(Pb + nl * 72 + rt * 16 + g * 4,
              L[rt][0] * rinv, L[rt][1] * rinv, L[rt][2] * rinv, L[rt][3] * rinv);
      floatx4 oacc[2];
      oacc[0] = (floatx4){0.f, 0.f, 0.f, 0.f};
      oacc[1] = (floatx4){0.f, 0.f, 0.f, 0.f};
#pragma unroll
      for (int ks = 0; ks < 2; ++ks) {
        const bf16x8 pf = *(const bf16x8*)(Pb + nl * 72 + ks * 32 + g * 8);
#pragma unroll
        for (int dt = 0; dt < 2; ++dt) {
          const bf16x8 vf = *(const bf16x8*)(Vt + (h * 32 + dt * 16 + nl) * 72 + ks * 32 + g * 8);
          oacc[dt] = __builtin_amdgcn_mfma_f32_16x16x32_bf16(vf, pf, oacc[dt], 0, 0, 0);
        }
      }
#pragma unroll
      for (int dt = 0; dt < 2; ++dt)
        st4bf(Xb + n * 200 + h * 32 + dt * 16 + g * 4,
              oacc[dt][0], oacc[dt][1], oacc[dt][2], oacc[dt][3]);
    }
  }
  __syncthreads();

  // ---- phase 4: out = AO @ Wp^T  (computed as out^T = Wp * AO^T)
  {
    bf16x8 af[4][6];
#pragma unroll
    for (int nt = 0; nt < 4; ++nt)
#pragma unroll
      for (int k = 0; k < 6; ++k)
        af[nt][k] = *(const bf16x8*)(Xb + (nt * 16 + nl) * 200 + k * 32 + g * 8);
    float* outb = out + (size_t)b * (NTOK * CDIM);
    const u16* wpb = w_bf + 3 * (CDIM * CDIM);
    for (int o = wave; o < 12; o += 8) {
      const u16* wb = wpb + (o * 16 + nl) * CDIM + g * 8;
      bf16x8 wf[6];
#pragma unroll
      for (int k = 0; k < 6; ++k) wf[k] = *(const bf16x8*)(wb + k * 32);
      floatx4 acc[4];
#pragma unroll
      for (int nt = 0; nt < 4; ++nt) acc[nt] = (floatx4){0.f, 0.f, 0.f, 0.f};
#pragma unroll
      for (int k = 0; k < 6; ++k)
#pragma unroll
        for (int nt = 0; nt < 4; ++nt)
          acc[nt] = __builtin_amdgcn_mfma_f32_16x16x32_bf16(wf[k], af[nt][k], acc[nt], 0, 0, 0);
#pragma unroll
      for (int nt = 0; nt < 4; ++nt) {
        const int n = nt * 16 + nl;
        if (n < 49) {
          float4 v;
          v.x = acc[nt][0]; v.y = acc[nt][1]; v.z = acc[nt][2]; v.w = acc[nt][3];
          *(float4*)(outb + n * CDIM + o * 16 + g * 4) = v;
        }
      }
    }
  }
}

extern "C" void kernel_launch(void* const* d_in, const int* in_sizes, int n_in,
                              void* d_out, int out_size, void* d_ws, size_t ws_size,
                              hipStream_t stream) {
  const float* x    = (const float*)d_in[0];
  const float* mask = (const float*)d_in[1];
  const float* dl   = (const float*)d_in[2];
  const float* Wq   = (const float*)d_in[3];
  const float* Wk   = (const float*)d_in[4];
  const float* Wv   = (const float*)d_in[5];
  const float* Wp   = (const float*)d_in[6];
  const float* temp = (const float*)d_in[7];
  const float* rpb  = (const float*)d_in[8];
  const int*   rel  = (const int*)d_in[9];

  u16* w_bf = (u16*)d_ws;
  float* bias = (float*)((char*)d_ws + (size_t)4 * CDIM * CDIM * sizeof(u16));
  float* o = (float*)d_out;

  (void)hipFuncSetAttribute((const void*)wattn_main,
                            hipFuncAttributeMaxDynamicSharedMemorySize, LDS_BYTES);

  wprep<<<256, 256, 0, stream>>>(Wq, Wk, Wv, Wp, rpb, rel, w_bf, bias);
  wattn_main<<<8192, 512, LDS_BYTES, stream>>>(x, mask, dl, temp, w_bf, bias, o);
}